// Round 18
// baseline (82.560 us; speedup 1.0000x reference)
//
#include <hip/hip_runtime.h>
#include <hip/hip_bf16.h>
#include <math.h>

#define FEAT 1024
#define HID  512
#define DK   256
#define NROWS 8192

typedef __attribute__((ext_vector_type(8))) short short8;
typedef __attribute__((ext_vector_type(4))) float floatx4;

// RNE float -> bf16 (raw u16).
__device__ __forceinline__ unsigned short f2bf(float x) {
    union { float f; unsigned u; } u;
    u.f = x;
    unsigned r = u.u;
    r += 0x7fffu + ((r >> 16) & 1u);
    return (unsigned short)(r >> 16);
}
__device__ __forceinline__ float bf2f(unsigned short x) {
    union { unsigned u; float f; } u;
    u.u = ((unsigned)x) << 16;
    return u.f;
}

__device__ __forceinline__ void gld_lds16(const unsigned short* g, unsigned short* l) {
    __builtin_amdgcn_global_load_lds(
        (__attribute__((address_space(1))) void*)(void*)g,
        (__attribute__((address_space(3))) void*)l,
        16, 0, 0);
}

__device__ __forceinline__ short8 cast8(float4 a, float4 b) {
    short8 r;
    r[0] = (short)f2bf(a.x); r[1] = (short)f2bf(a.y);
    r[2] = (short)f2bf(a.z); r[3] = (short)f2bf(a.w);
    r[4] = (short)f2bf(b.x); r[5] = (short)f2bf(b.y);
    r[6] = (short)f2bf(b.z); r[7] = (short)f2bf(b.w);
    return r;
}

// ---------------------------------------------------------------------------
// prep: 4 weight transposes (f32 [K][N] -> bf16 [N][K]) + zero P/Z/counter.
// ---------------------------------------------------------------------------
__global__ __launch_bounds__(256) void prep_kernel(
    const float* __restrict__ W1, const float* __restrict__ Wq,
    const float* __restrict__ Wk, const float* __restrict__ Wv,
    unsigned short* __restrict__ W1T, unsigned short* __restrict__ WqT,
    unsigned short* __restrict__ WkT, unsigned short* __restrict__ WvT,
    float* __restrict__ P, float* __restrict__ Z, unsigned* __restrict__ counter)
{
    const int b = blockIdx.x;
    const int tid = threadIdx.x;

    if (b == 0) {
        for (int i = tid; i < 3 * DK; i += 256) P[i] = 0.f;
        if (tid < 3) Z[tid] = 0.f;
        if (tid == 0) *counter = 0u;
    }

    int t = b;
    const float* in; unsigned short* outp; int K, N, tn, tk;
    if (t < 512) {                  // W1: 16 n-tiles x 32 k-tiles
        in = W1; outp = W1T; K = FEAT; N = HID; tn = t & 15; tk = t >> 4;
    } else {                        // Wq/Wk/Wv: 8 n-tiles x 16 k-tiles each
        t -= 512;
        int z = t >> 7, r = t & 127;
        K = HID; N = DK; tn = r & 7; tk = r >> 3;
        in   = (z == 0) ? Wq  : (z == 1) ? Wk  : Wv;
        outp = (z == 0) ? WqT : (z == 1) ? WkT : WvT;
    }
    __shared__ float tt[32][33];
    const int tx = tid & 31, ty = tid >> 5;
    const int n0 = tn * 32, k0 = tk * 32;
    #pragma unroll
    for (int i2 = ty; i2 < 32; i2 += 8)
        tt[i2][tx] = in[(size_t)(k0 + i2) * N + (n0 + tx)];
    __syncthreads();
    #pragma unroll
    for (int i2 = ty; i2 < 32; i2 += 8)
        outp[(size_t)(n0 + i2) * K + (k0 + tx)] = f2bf(tt[tx][i2]);
}

// ---------------------------------------------------------------------------
// BARRIER-FREE per-wave MFMA GEMM (r17 design, RACE FIXED).
// r17's absmax=0.19 failure: global_load_lds increments VMCNT; the compiler
// cannot see aliasing between a gld_lds LDS-write and a later raw-pointer
// ds_read, so it inserts no vmcnt wait — __syncthreads had been providing
// that drain in every earlier (correct) version. Fix: explicit
// s_waitcnt vmcnt(0) lgkmcnt(0) + sched_barrier(0) (rule #18) immediately
// before the fragment reads.
// Design: each wave owns a PRIVATE 8 KB LDS region staging its own 32x64
// A-slice + 32x64 B-slice; ZERO block barriers; each wave waits only on its
// OWN loads, so the CU's resident waves overlap stalls independently (m114).
// 64x64 block tile (4 waves x 32x32), BK=64, axis-swapped grid. XOR swizzle
// LDS[row][g] = src[row][g^(row&7)]; frag reads XOR same mask. Per-fragment
// K accumulation order identical to r12/r16 -> bit-identical output.
// A_F32=1: fp32 A reg-staged (loads issued with next tile; ds_write at top
//          of next iter). A_F32=0: bf16 A via gld_lds, swizzled source.
// ---------------------------------------------------------------------------
template<int A_F32>
__global__ __launch_bounds__(256) void gemm_mfma(
    const void* __restrict__ Av,
    const unsigned short* __restrict__ BT0, const unsigned short* __restrict__ BT1,
    const unsigned short* __restrict__ BT2,
    const float* __restrict__ bias0, const float* __restrict__ bias1,
    const float* __restrict__ bias2,
    unsigned short* __restrict__ C0, unsigned short* __restrict__ C1,
    unsigned short* __restrict__ C2,
    int N, int K, int relu)
{
    const int z = blockIdx.z;
    const unsigned short* BT = (z == 0) ? BT0 : (z == 1) ? BT1 : BT2;
    const float* bias        = (z == 0) ? bias0 : (z == 1) ? bias1 : bias2;
    unsigned short* C        = (z == 0) ? C0 : (z == 1) ? C1 : C2;

    __shared__ __align__(16) unsigned short Lds[4 * 4096];  // 4 waves x 8 KB

    const int tid  = threadIdx.x;
    const int lane = tid & 63;
    const int wid  = tid >> 6;
    const int wm = wid >> 1, wn = wid & 1;
    const int m0 = blockIdx.x * 64;      // by fastest (axis swap)
    const int n0 = blockIdx.y * 64;      // bx slow

    char* AW = (char*)Lds + wid * 8192;        // wave's A region (4 KB)
    char* BW = AW + 4096;                       // wave's B region (4 KB)

    // Per-wave staging: 32 rows x 8 granules = 256 granules, 4 passes of 64.
    // pass p, lane l: idx = p*64+l; row = idx>>3; g = idx&7.
    // gld_lds dest (linear): base + p*1024 + l*16 = row*128 + g*16.
    int rowp[4], gp[4];
    const float*          ApF[4];
    const unsigned short* ApB[4];
    const unsigned short* Bp[4];
    #pragma unroll
    for (int p = 0; p < 4; ++p) {
        int idx = p * 64 + lane;
        int row = idx >> 3, g = idx & 7;
        int sg = g ^ (row & 7);
        rowp[p] = row; gp[p] = g;
        ApF[p] = (const float*)Av + (size_t)(m0 + wm * 32 + row) * K + g * 8;
        ApB[p] = (const unsigned short*)Av + (size_t)(m0 + wm * 32 + row) * K + sg * 8;
        Bp[p]  = BT + (size_t)(n0 + wn * 32 + row) * K + sg * 8;
    }

    // Fragment ds_read byte offsets within wave region: [ksub][frag].
    int aoff[2][2];
    #pragma unroll
    for (int ks = 0; ks < 2; ++ks) {
        int gk = ks * 4 + (lane >> 4);
        #pragma unroll
        for (int i = 0; i < 2; ++i) {
            int ra = i * 16 + (lane & 15);          // row within wave's 32
            aoff[ks][i] = ra * 128 + ((gk ^ (ra & 7)) * 16);
        }
    }

    floatx4 acc[2][2];
    #pragma unroll
    for (int i = 0; i < 2; ++i)
        #pragma unroll
        for (int jj = 0; jj < 2; ++jj)
            acc[i][jj] = (floatx4){0.f, 0.f, 0.f, 0.f};

    // ---- prologue: issue loads for tile 0 ----
    float4 ar0[4], ar1[4];
    if (A_F32) {
        #pragma unroll
        for (int p = 0; p < 4; ++p) {
            ar0[p] = *(const float4*)(ApF[p]);
            ar1[p] = *(const float4*)(ApF[p] + 4);
        }
        #pragma unroll
        for (int p = 0; p < 4; ++p)
            gld_lds16(Bp[p], (unsigned short*)(BW + p * 1024));
    } else {
        #pragma unroll
        for (int p = 0; p < 4; ++p)
            gld_lds16(ApB[p], (unsigned short*)(AW + p * 1024));
        #pragma unroll
        for (int p = 0; p < 4; ++p)
            gld_lds16(Bp[p], (unsigned short*)(BW + p * 1024));
    }

    for (int kt = 0; kt < K; kt += 64) {
        // A_F32: commit reg-staged A(t) to LDS (reg data dep waits the loads).
        if (A_F32) {
            #pragma unroll
            for (int p = 0; p < 4; ++p)
                *(short8*)(AW + rowp[p] * 128 + (gp[p] ^ (rowp[p] & 7)) * 16)
                    = cast8(ar0[p], ar1[p]);
        }

        // RACE FIX: drain this wave's outstanding gld_lds (vmcnt) and LDS
        // writes (lgkmcnt) before reading the region. sched_barrier pins it.
        asm volatile("s_waitcnt vmcnt(0) lgkmcnt(0)" ::: "memory");
        __builtin_amdgcn_sched_barrier(0);

        // Read ALL fragments for this tile.
        short8 af[2][2], bfr[2][2];
        #pragma unroll
        for (int ks = 0; ks < 2; ++ks)
            #pragma unroll
            for (int i = 0; i < 2; ++i) {
                af[ks][i]  = *(const short8*)(AW + aoff[ks][i]);
                bfr[ks][i] = *(const short8*)(BW + aoff[ks][i]);
            }

        // Drain reads -> WAR-safe to overwrite region with next tile.
        asm volatile("s_waitcnt lgkmcnt(0)" ::: "memory");
        __builtin_amdgcn_sched_barrier(0);

        if (kt + 64 < K) {
            if (A_F32) {
                #pragma unroll
                for (int p = 0; p < 4; ++p) {
                    ar0[p] = *(const float4*)(ApF[p] + kt + 64);
                    ar1[p] = *(const float4*)(ApF[p] + kt + 64 + 4);
                }
                #pragma unroll
                for (int p = 0; p < 4; ++p)
                    gld_lds16(Bp[p] + kt + 64, (unsigned short*)(BW + p * 1024));
            } else {
                #pragma unroll
                for (int p = 0; p < 4; ++p)
                    gld_lds16(ApB[p] + kt + 64, (unsigned short*)(AW + p * 1024));
                #pragma unroll
                for (int p = 0; p < 4; ++p)
                    gld_lds16(Bp[p] + kt + 64, (unsigned short*)(BW + p * 1024));
            }
        }

        // MFMA on registers (overlaps the in-flight loads of tile t+1).
        #pragma unroll
        for (int ks = 0; ks < 2; ++ks)
            #pragma unroll
            for (int i = 0; i < 2; ++i)
                #pragma unroll
                for (int jj = 0; jj < 2; ++jj)
                    acc[i][jj] = __builtin_amdgcn_mfma_f32_16x16x32_bf16(
                        af[ks][i], bfr[ks][jj], acc[i][jj], 0, 0, 0);
    }

    // Epilogue: C/D layout col = lane&15, row = (lane>>4)*4 + reg. bf16 out.
    #pragma unroll
    for (int i = 0; i < 2; ++i) {
        int rbase = m0 + wm * 32 + i * 16 + (lane >> 4) * 4;
        #pragma unroll
        for (int jj = 0; jj < 2; ++jj) {
            int c = n0 + wn * 32 + jj * 16 + (lane & 15);
            float bb = bias ? bias[c] : 0.f;
            #pragma unroll
            for (int r = 0; r < 4; ++r) {
                float v = acc[i][jj][r] + bb;
                if (relu) v = fmaxf(v, 0.f);
                C[(size_t)(rbase + r) * N + c] = f2bf(v);
            }
        }
    }
}

// ---------------------------------------------------------------------------
// Gather: 2048 blocks x 4 waves, one row per wave (full TLP — scattered
// K-row reads are latency-bound). No max tracking (fixed-shift softmax).
// NO threadfence here — r14 showed 2048 device-scope fences cost ~200 us.
// ---------------------------------------------------------------------------
__global__ __launch_bounds__(256) void gather_attn(
    const unsigned short* __restrict__ Q, const unsigned short* __restrict__ Kmat,
    const int* __restrict__ sp, float* __restrict__ a_raw)
{
    const int lane = threadIdx.x & 63;
    const int wid  = threadIdx.x >> 6;
    const int i = blockIdx.x * 4 + wid;

    ushort4 qr = *(const ushort4*)(Q + (size_t)i * DK + lane * 4);
    float4 q = make_float4(bf2f(qr.x), bf2f(qr.y), bf2f(qr.z), bf2f(qr.w));
    float4 ks = make_float4(0.f, 0.f, 0.f, 0.f);

    int sel = 0;
    #pragma unroll
    for (int j = 0; j <= 8; ++j) {
        int r = sp[i * 9 + j];
        ushort4 kr = *(const ushort4*)(Kmat + (size_t)r * DK + lane * 4);
        ks.x += bf2f(kr.x); ks.y += bf2f(kr.y);
        ks.z += bf2f(kr.z); ks.w += bf2f(kr.w);
        if (j == 2 || j == 4 || j == 8) {
            float d = q.x * ks.x + q.y * ks.y + q.z * ks.z + q.w * ks.w;
            #pragma unroll
            for (int off = 32; off; off >>= 1) d += __shfl_xor(d, off);
            if (lane == 0) a_raw[sel * NROWS + i] = d * 0.0625f;  // /sqrt(256)
            ++sel;
        }
    }
}

// ---------------------------------------------------------------------------
// Pools (one V pass, all 3 selectors) + folded final epilogue via ticket
// (128 blocks — fence count at this scale measured fine in r12).
// Fixed-shift softmax: e = exp(a_raw - SHIFT); SHIFT cancels in P/Z.
// ---------------------------------------------------------------------------
#define RPB 64
#define SM_SHIFT 10.0f
__global__ __launch_bounds__(256) void pool_kernel(
    const float* __restrict__ a_raw,
    const unsigned short* __restrict__ V, float* __restrict__ P,
    float* __restrict__ Z, unsigned* __restrict__ counter,
    const float* __restrict__ Wout, const float* __restrict__ bout,
    float* __restrict__ out)
{
    const int r0 = blockIdx.x * RPB;
    const int t = threadIdx.x;

    __shared__ float red[2][256];
    __shared__ float e[3][RPB];
    __shared__ unsigned rank;
    __shared__ float zz[3];

    float z0 = 0.f, z1 = 0.f, z2 = 0.f;
    if (t < RPB) {
        z0 = expf(a_raw[0 * NROWS + r0 + t] - SM_SHIFT);
        z1 = expf(a_raw[1 * NROWS + r0 + t] - SM_SHIFT);
        z2 = expf(a_raw[2 * NROWS + r0 + t] - SM_SHIFT);
        e[0][t] = z0; e[1][t] = z1; e[2][t] = z2;
    }
    __syncthreads();

    float a0 = 0.f, a1 = 0.f, a2 = 0.f;
    for (int r = 0; r < RPB; ++r) {
        float v = bf2f(V[(size_t)(r0 + r) * DK + t]);
        a0 = fmaf(e[0][r], v, a0);
        a1 = fmaf(e[1][r], v, a1);
        a2 = fmaf(e[2][r], v, a2);
    }
    atomicAdd(&P[0 * DK + t], a0);
    atomicAdd(&P[1 * DK + t], a1);
    atomicAdd(&P[2 * DK + t], a2);

    #pragma unroll
    for (int off = 32; off; off >>= 1) {
        z0 += __shfl_xor(z0, off); z1 += __shfl_xor(z1, off); z2 += __shfl_xor(z2, off);
    }
    if (t == 0) {
        atomicAdd(&Z[0], z0); atomicAdd(&Z[1], z1); atomicAdd(&Z[2], z2);
    }

    // ---- ticket: last block computes the final 2-class softmax ----
    __threadfence();
    if (t == 0) rank = atomicAdd(counter, 1u);
    __syncthreads();
    if (rank == gridDim.x - 1) {
        __threadfence();
        if (t < 3) zz[t] = atomicAdd(&Z[t], 0.0f);   // atomic read: coherent
        __syncthreads();
        float p0 = atomicAdd(&P[0 * DK + t], 0.0f);
        float p1 = atomicAdd(&P[1 * DK + t], 0.0f);
        float p2 = atomicAdd(&P[2 * DK + t], 0.0f);
        float s = p0 / zz[0] + p1 / zz[1] + p2 / zz[2];
        red[0][t] = s * Wout[t * 2 + 0];
        red[1][t] = s * Wout[t * 2 + 1];
        __syncthreads();
        for (int st = 128; st; st >>= 1) {
            if (t < st) {
                red[0][t] += red[0][t + st];
                red[1][t] += red[1][t + st];
            }
            __syncthreads();
        }
        if (t == 0) {
            float a = red[0][0] + bout[0], b = red[1][0] + bout[1];
            float mm = fmaxf(a, b);
            float ea = expf(a - mm), eb = expf(b - mm);
            float inv = 1.f / (ea + eb);
            out[0] = ea * inv;
            out[1] = eb * inv;
        }
    }
}

// ---------------------------------------------------------------------------
extern "C" void kernel_launch(void* const* d_in, const int* in_sizes, int n_in,
                              void* d_out, int out_size, void* d_ws, size_t ws_size,
                              hipStream_t stream)
{
    const float* X    = (const float*)d_in[0];   // 8192 x 1024
    const int*   sp   = (const int*)  d_in[1];   // 8192 x 9
    const float* W1   = (const float*)d_in[2];   // 1024 x 512
    const float* b1   = (const float*)d_in[3];   // 512
    const float* Wq   = (const float*)d_in[4];   // 512 x 256
    const float* Wk   = (const float*)d_in[5];
    const float* Wv   = (const float*)d_in[6];
    const float* bv   = (const float*)d_in[7];   // 256
    const float* Wout = (const float*)d_in[8];   // 256 x 2
    const float* bout = (const float*)d_in[9];   // 2
    float* out = (float*)d_out;

    // Workspace layout (bytes). No Xb.
    char* w = (char*)d_ws;
    unsigned short* dense_b = (unsigned short*)(w);             // 8192x512 bf16
    unsigned short* W1T     = (unsigned short*)(w +  8388608);  // 512x1024 bf16
    unsigned short* WqT     = (unsigned short*)(w +  9437184);  // 256x512 bf16
    unsigned short* WkT     = (unsigned short*)(w +  9699328);
    unsigned short* WvT     = (unsigned short*)(w +  9961472);
    float* a_raw            = (float*)(w + 10223616);           // 3*8192 f32
    float* P                = (float*)(w + 10321920);           // 3*256 f32
    float* Z                = P + 3 * DK;                       // 3
    unsigned* counter       = (unsigned*)(Z + 3);               // 1
    unsigned short* Qb      = (unsigned short*)(w + 10485760);  // 8192x256 bf16
    unsigned short* Kb      = (unsigned short*)(w + 14680064);
    unsigned short* Vb      = (unsigned short*)(w + 18874368);

    // 0) prep: weight transposes + zero accumulators/ticket (1 small launch)
    prep_kernel<<<896, 256, 0, stream>>>(
        W1, Wq, Wk, Wv, W1T, WqT, WkT, WvT, P, Z, counter);

    // 1) dense_b = bf16(relu(X @ W1 + b1)) — fp32 X direct; barrier-free
    gemm_mfma<1><<<dim3(NROWS / 64, HID / 64, 1), 256, 0, stream>>>(
        X, W1T, nullptr, nullptr, b1, nullptr, nullptr,
        dense_b, nullptr, nullptr, HID, FEAT, 1);

    // 2) Q/K/V = bf16(dense @ {Wq,Wk,Wv} (+bv on V)); barrier-free
    gemm_mfma<0><<<dim3(NROWS / 64, DK / 64, 3), 256, 0, stream>>>(
        dense_b, WqT, WkT, WvT, nullptr, nullptr, bv,
        Qb, Kb, Vb, DK, HID, 0);

    // 3) a_raw (one wave per row, full TLP)
    gather_attn<<<NROWS / 4, 256, 0, stream>>>(Qb, Kb, sp, a_raw);
    // 4) pooled weighted sums + folded final epilogue (ticket)
    pool_kernel<<<NROWS / RPB, 256, 0, stream>>>(
        a_raw, Vb, P, Z, counter, Wout, bout, out);
}

// Round 19
// 69.401 us; speedup vs baseline: 1.1896x; 1.1896x over previous
//
#include <hip/hip_runtime.h>
#include <hip/hip_bf16.h>
#include <math.h>

#define FEAT 1024
#define HID  512
#define DK   256
#define NROWS 8192

typedef __attribute__((ext_vector_type(8))) short short8;
typedef __attribute__((ext_vector_type(4))) float floatx4;

// RNE float -> bf16 (raw u16).
__device__ __forceinline__ unsigned short f2bf(float x) {
    union { float f; unsigned u; } u;
    u.f = x;
    unsigned r = u.u;
    r += 0x7fffu + ((r >> 16) & 1u);
    return (unsigned short)(r >> 16);
}
__device__ __forceinline__ float bf2f(unsigned short x) {
    union { unsigned u; float f; } u;
    u.u = ((unsigned)x) << 16;
    return u.f;
}

__device__ __forceinline__ void gld_lds16(const unsigned short* g, unsigned short* l) {
    __builtin_amdgcn_global_load_lds(
        (__attribute__((address_space(1))) void*)(void*)g,
        (__attribute__((address_space(3))) void*)l,
        16, 0, 0);
}

__device__ __forceinline__ short8 cast8(float4 a, float4 b) {
    short8 r;
    r[0] = (short)f2bf(a.x); r[1] = (short)f2bf(a.y);
    r[2] = (short)f2bf(a.z); r[3] = (short)f2bf(a.w);
    r[4] = (short)f2bf(b.x); r[5] = (short)f2bf(b.y);
    r[6] = (short)f2bf(b.z); r[7] = (short)f2bf(b.w);
    return r;
}

// ---------------------------------------------------------------------------
// prep: 4 weight transposes (f32 [K][N] -> bf16 [N][K]) + zero P/Z/counter.
// ---------------------------------------------------------------------------
__global__ __launch_bounds__(256) void prep_kernel(
    const float* __restrict__ W1, const float* __restrict__ Wq,
    const float* __restrict__ Wk, const float* __restrict__ Wv,
    unsigned short* __restrict__ W1T, unsigned short* __restrict__ WqT,
    unsigned short* __restrict__ WkT, unsigned short* __restrict__ WvT,
    float* __restrict__ P, float* __restrict__ Z, unsigned* __restrict__ counter)
{
    const int b = blockIdx.x;
    const int tid = threadIdx.x;

    if (b == 0) {
        for (int i = tid; i < 3 * DK; i += 256) P[i] = 0.f;
        if (tid < 3) Z[tid] = 0.f;
        if (tid == 0) *counter = 0u;
    }

    int t = b;
    const float* in; unsigned short* outp; int K, N, tn, tk;
    if (t < 512) {                  // W1: 16 n-tiles x 32 k-tiles
        in = W1; outp = W1T; K = FEAT; N = HID; tn = t & 15; tk = t >> 4;
    } else {                        // Wq/Wk/Wv: 8 n-tiles x 16 k-tiles each
        t -= 512;
        int z = t >> 7, r = t & 127;
        K = HID; N = DK; tn = r & 7; tk = r >> 3;
        in   = (z == 0) ? Wq  : (z == 1) ? Wk  : Wv;
        outp = (z == 0) ? WqT : (z == 1) ? WkT : WvT;
    }
    __shared__ float tt[32][33];
    const int tx = tid & 31, ty = tid >> 5;
    const int n0 = tn * 32, k0 = tk * 32;
    #pragma unroll
    for (int i2 = ty; i2 < 32; i2 += 8)
        tt[i2][tx] = in[(size_t)(k0 + i2) * N + (n0 + tx)];
    __syncthreads();
    #pragma unroll
    for (int i2 = ty; i2 < 32; i2 += 8)
        outp[(size_t)(n0 + i2) * K + (k0 + tx)] = f2bf(tt[tx][i2]);
}

// ---------------------------------------------------------------------------
// MFMA bf16 GEMM — r12 configuration (session optimum: 69.8 us). BK=64,
// single-buffer, two barriers/iter. Structure-ledger (12 experiments):
// BK{32,64,128}={75.1,69.8,73.2}; +dbuf +3.6; 64x64 tile +1.2; XCD-remap +7;
// barrier-free +12.8. Axis-swapped grid: by (M-tile) = blockIdx.x FASTEST ->
// A-tile sharers at flat-id distance 128 (mult of 8) land on one XCD
// (r11-verified: fetch 66->20 MB). Both-sides XOR swizzle, 8 granules/row:
// LDS[row][g] = src[row][g ^ (row&7)]; frag reads XOR same mask -> <=2-way
// bank conflict (free). 64x128 tile, 4 waves (2x2), 2x4 16x16x32 frags.
// A_F32=1: fp32 A reg-staged (load+cast8+swizzled ds_write — kills the
//          separate X-cast pass). A_F32=0: bf16 A via gld_lds, swz source.
// Remaining known stall: compiler's vmcnt(0) drain at the barrier (guide §5
// ~20% structural); counted-vmcnt pipelining = high-risk rewrite, declined.
// ---------------------------------------------------------------------------
template<int A_F32>
__global__ __launch_bounds__(256) void gemm_mfma(
    const void* __restrict__ Av,
    const unsigned short* __restrict__ BT0, const unsigned short* __restrict__ BT1,
    const unsigned short* __restrict__ BT2,
    const float* __restrict__ bias0, const float* __restrict__ bias1,
    const float* __restrict__ bias2,
    unsigned short* __restrict__ C0, unsigned short* __restrict__ C1,
    unsigned short* __restrict__ C2,
    int N, int K, int relu)
{
    const int z = blockIdx.z;
    const unsigned short* BT = (z == 0) ? BT0 : (z == 1) ? BT1 : BT2;
    const float* bias        = (z == 0) ? bias0 : (z == 1) ? bias1 : bias2;
    unsigned short* C        = (z == 0) ? C0 : (z == 1) ? C1 : C2;

    __shared__ __align__(16) unsigned short As[64 * 64];     // 8 KB
    __shared__ __align__(16) unsigned short Bs[128 * 64];    // 16 KB

    const int tid  = threadIdx.x;
    const int lane = tid & 63;
    const int wid  = tid >> 6;
    const int wm = wid >> 1, wn = wid & 1;
    const int m0 = blockIdx.x * 64;      // by fastest (axis swap)
    const int n0 = blockIdx.y * 128;     // bx slow

    // A staging: 64 rows x 8 granules (granule = 8 elems) = 512, 2 passes.
    int arowp[2], asgp[2];
    const float*          ApF[2];
    const unsigned short* ApB[2];
    #pragma unroll
    for (int p = 0; p < 2; ++p) {
        int idx = p * 256 + tid;
        int row = idx >> 3, g = idx & 7;
        int sg = g ^ (row & 7);
        arowp[p] = row; asgp[p] = sg;
        ApF[p] = (const float*)Av + (size_t)(m0 + row) * K + g * 8;            // linear src
        ApB[p] = (const unsigned short*)Av + (size_t)(m0 + row) * K + sg * 8;  // swz src
    }
    // B staging: 128 rows x 8 granules = 1024, 4 passes, swizzled source.
    const unsigned short* Bp[4];
    #pragma unroll
    for (int p = 0; p < 4; ++p) {
        int idx = p * 256 + tid;
        int row = idx >> 3, g = idx & 7;
        int sg = g ^ (row & 7);
        Bp[p] = BT + (size_t)(n0 + row) * K + sg * 8;
    }

    char* AsB = (char*)As;
    char* BsB = (char*)Bs;

    // Fragment ds_read byte offsets: [ksub][frag], swizzled. Row = 128 B.
    const int gr = lane >> 4;
    int aoff[2][2], boff[2][4];
    #pragma unroll
    for (int ks = 0; ks < 2; ++ks) {
        int gk = ks * 4 + gr;
        #pragma unroll
        for (int i = 0; i < 2; ++i) {
            int ra = wm * 32 + i * 16 + (lane & 15);
            aoff[ks][i] = ra * 128 + ((gk ^ (ra & 7)) * 16);
        }
        #pragma unroll
        for (int jj = 0; jj < 4; ++jj) {
            int rb = wn * 64 + jj * 16 + (lane & 15);
            boff[ks][jj] = rb * 128 + ((gk ^ (rb & 7)) * 16);
        }
    }

    floatx4 acc[2][4];
    #pragma unroll
    for (int i = 0; i < 2; ++i)
        #pragma unroll
        for (int jj = 0; jj < 4; ++jj)
            acc[i][jj] = (floatx4){0.f, 0.f, 0.f, 0.f};

    for (int kt = 0; kt < K; kt += 64) {
        if (A_F32) {
            float4 a00 = *(const float4*)(ApF[0] + kt);
            float4 a01 = *(const float4*)(ApF[0] + kt + 4);
            float4 a10 = *(const float4*)(ApF[1] + kt);
            float4 a11 = *(const float4*)(ApF[1] + kt + 4);
            #pragma unroll
            for (int p = 0; p < 4; ++p)
                gld_lds16(Bp[p] + kt, (unsigned short*)(BsB + p * 4096 + wid * 1024));
            *(short8*)(AsB + arowp[0] * 128 + asgp[0] * 16) = cast8(a00, a01);
            *(short8*)(AsB + arowp[1] * 128 + asgp[1] * 16) = cast8(a10, a11);
        } else {
            #pragma unroll
            for (int p = 0; p < 2; ++p)
                gld_lds16(ApB[p] + kt, (unsigned short*)(AsB + p * 4096 + wid * 1024));
            #pragma unroll
            for (int p = 0; p < 4; ++p)
                gld_lds16(Bp[p] + kt, (unsigned short*)(BsB + p * 4096 + wid * 1024));
        }
        __syncthreads();   // drains vmcnt/lgkm: LDS tiles resident

        #pragma unroll
        for (int ks = 0; ks < 2; ++ks) {
            short8 af[2], bfr[4];
            #pragma unroll
            for (int i = 0; i < 2; ++i) af[i] = *(const short8*)(AsB + aoff[ks][i]);
            #pragma unroll
            for (int jj = 0; jj < 4; ++jj) bfr[jj] = *(const short8*)(BsB + boff[ks][jj]);
            #pragma unroll
            for (int i = 0; i < 2; ++i)
                #pragma unroll
                for (int jj = 0; jj < 4; ++jj)
                    acc[i][jj] = __builtin_amdgcn_mfma_f32_16x16x32_bf16(
                        af[i], bfr[jj], acc[i][jj], 0, 0, 0);
        }
        __syncthreads();   // protect LDS before next stage
    }

    // Epilogue: C/D layout col = lane&15, row = (lane>>4)*4 + reg. bf16 out.
    #pragma unroll
    for (int i = 0; i < 2; ++i) {
        int rbase = m0 + wm * 32 + i * 16 + (lane >> 4) * 4;
        #pragma unroll
        for (int jj = 0; jj < 4; ++jj) {
            int c = n0 + wn * 64 + jj * 16 + (lane & 15);
            float bb = bias ? bias[c] : 0.f;
            #pragma unroll
            for (int r = 0; r < 4; ++r) {
                float v = acc[i][jj][r] + bb;
                if (relu) v = fmaxf(v, 0.f);
                C[(size_t)(rbase + r) * N + c] = f2bf(v);
            }
        }
    }
}

// ---------------------------------------------------------------------------
// Gather: 2048 blocks x 4 waves, one row per wave (full TLP — scattered
// K-row reads are latency-bound). No max tracking (fixed-shift softmax).
// NO threadfence here — r14 showed 2048 device-scope fences cost ~200 us.
// ---------------------------------------------------------------------------
__global__ __launch_bounds__(256) void gather_attn(
    const unsigned short* __restrict__ Q, const unsigned short* __restrict__ Kmat,
    const int* __restrict__ sp, float* __restrict__ a_raw)
{
    const int lane = threadIdx.x & 63;
    const int wid  = threadIdx.x >> 6;
    const int i = blockIdx.x * 4 + wid;

    ushort4 qr = *(const ushort4*)(Q + (size_t)i * DK + lane * 4);
    float4 q = make_float4(bf2f(qr.x), bf2f(qr.y), bf2f(qr.z), bf2f(qr.w));
    float4 ks = make_float4(0.f, 0.f, 0.f, 0.f);

    int sel = 0;
    #pragma unroll
    for (int j = 0; j <= 8; ++j) {
        int r = sp[i * 9 + j];
        ushort4 kr = *(const ushort4*)(Kmat + (size_t)r * DK + lane * 4);
        ks.x += bf2f(kr.x); ks.y += bf2f(kr.y);
        ks.z += bf2f(kr.z); ks.w += bf2f(kr.w);
        if (j == 2 || j == 4 || j == 8) {
            float d = q.x * ks.x + q.y * ks.y + q.z * ks.z + q.w * ks.w;
            #pragma unroll
            for (int off = 32; off; off >>= 1) d += __shfl_xor(d, off);
            if (lane == 0) a_raw[sel * NROWS + i] = d * 0.0625f;  // /sqrt(256)
            ++sel;
        }
    }
}

// ---------------------------------------------------------------------------
// Pools (one V pass, all 3 selectors) + folded final epilogue via ticket
// (128 blocks — fence count at this scale measured fine in r12).
// Fixed-shift softmax: e = exp(a_raw - SHIFT); SHIFT cancels in P/Z.
// ---------------------------------------------------------------------------
#define RPB 64
#define SM_SHIFT 10.0f
__global__ __launch_bounds__(256) void pool_kernel(
    const float* __restrict__ a_raw,
    const unsigned short* __restrict__ V, float* __restrict__ P,
    float* __restrict__ Z, unsigned* __restrict__ counter,
    const float* __restrict__ Wout, const float* __restrict__ bout,
    float* __restrict__ out)
{
    const int r0 = blockIdx.x * RPB;
    const int t = threadIdx.x;

    __shared__ float red[2][256];
    __shared__ float e[3][RPB];
    __shared__ unsigned rank;
    __shared__ float zz[3];

    float z0 = 0.f, z1 = 0.f, z2 = 0.f;
    if (t < RPB) {
        z0 = expf(a_raw[0 * NROWS + r0 + t] - SM_SHIFT);
        z1 = expf(a_raw[1 * NROWS + r0 + t] - SM_SHIFT);
        z2 = expf(a_raw[2 * NROWS + r0 + t] - SM_SHIFT);
        e[0][t] = z0; e[1][t] = z1; e[2][t] = z2;
    }
    __syncthreads();

    float a0 = 0.f, a1 = 0.f, a2 = 0.f;
    for (int r = 0; r < RPB; ++r) {
        float v = bf2f(V[(size_t)(r0 + r) * DK + t]);
        a0 = fmaf(e[0][r], v, a0);
        a1 = fmaf(e[1][r], v, a1);
        a2 = fmaf(e[2][r], v, a2);
    }
    atomicAdd(&P[0 * DK + t], a0);
    atomicAdd(&P[1 * DK + t], a1);
    atomicAdd(&P[2 * DK + t], a2);

    #pragma unroll
    for (int off = 32; off; off >>= 1) {
        z0 += __shfl_xor(z0, off); z1 += __shfl_xor(z1, off); z2 += __shfl_xor(z2, off);
    }
    if (t == 0) {
        atomicAdd(&Z[0], z0); atomicAdd(&Z[1], z1); atomicAdd(&Z[2], z2);
    }

    // ---- ticket: last block computes the final 2-class softmax ----
    __threadfence();
    if (t == 0) rank = atomicAdd(counter, 1u);
    __syncthreads();
    if (rank == gridDim.x - 1) {
        __threadfence();
        if (t < 3) zz[t] = atomicAdd(&Z[t], 0.0f);   // atomic read: coherent
        __syncthreads();
        float p0 = atomicAdd(&P[0 * DK + t], 0.0f);
        float p1 = atomicAdd(&P[1 * DK + t], 0.0f);
        float p2 = atomicAdd(&P[2 * DK + t], 0.0f);
        float s = p0 / zz[0] + p1 / zz[1] + p2 / zz[2];
        red[0][t] = s * Wout[t * 2 + 0];
        red[1][t] = s * Wout[t * 2 + 1];
        __syncthreads();
        for (int st = 128; st; st >>= 1) {
            if (t < st) {
                red[0][t] += red[0][t + st];
                red[1][t] += red[1][t + st];
            }
            __syncthreads();
        }
        if (t == 0) {
            float a = red[0][0] + bout[0], b = red[1][0] + bout[1];
            float mm = fmaxf(a, b);
            float ea = expf(a - mm), eb = expf(b - mm);
            float inv = 1.f / (ea + eb);
            out[0] = ea * inv;
            out[1] = eb * inv;
        }
    }
}

// ---------------------------------------------------------------------------
extern "C" void kernel_launch(void* const* d_in, const int* in_sizes, int n_in,
                              void* d_out, int out_size, void* d_ws, size_t ws_size,
                              hipStream_t stream)
{
    const float* X    = (const float*)d_in[0];   // 8192 x 1024
    const int*   sp   = (const int*)  d_in[1];   // 8192 x 9
    const float* W1   = (const float*)d_in[2];   // 1024 x 512
    const float* b1   = (const float*)d_in[3];   // 512
    const float* Wq   = (const float*)d_in[4];   // 512 x 256
    const float* Wk   = (const float*)d_in[5];
    const float* Wv   = (const float*)d_in[6];
    const float* bv   = (const float*)d_in[7];   // 256
    const float* Wout = (const float*)d_in[8];   // 256 x 2
    const float* bout = (const float*)d_in[9];   // 2
    float* out = (float*)d_out;

    // Workspace layout (bytes). No Xb.
    char* w = (char*)d_ws;
    unsigned short* dense_b = (unsigned short*)(w);             // 8192x512 bf16
    unsigned short* W1T     = (unsigned short*)(w +  8388608);  // 512x1024 bf16
    unsigned short* WqT     = (unsigned short*)(w +  9437184);  // 256x512 bf16
    unsigned short* WkT     = (unsigned short*)(w +  9699328);
    unsigned short* WvT     = (unsigned short*)(w +  9961472);
    float* a_raw            = (float*)(w + 10223616);           // 3*8192 f32
    float* P                = (float*)(w + 10321920);           // 3*256 f32
    float* Z                = P + 3 * DK;                       // 3
    unsigned* counter       = (unsigned*)(Z + 3);               // 1
    unsigned short* Qb      = (unsigned short*)(w + 10485760);  // 8192x256 bf16
    unsigned short* Kb      = (unsigned short*)(w + 14680064);
    unsigned short* Vb      = (unsigned short*)(w + 18874368);

    // 0) prep: weight transposes + zero accumulators/ticket (1 small launch)
    prep_kernel<<<896, 256, 0, stream>>>(
        W1, Wq, Wk, Wv, W1T, WqT, WkT, WvT, P, Z, counter);

    // 1) dense_b = bf16(relu(X @ W1 + b1)) — fp32 X direct; BK=64, 16 iters
    gemm_mfma<1><<<dim3(NROWS / 64, HID / 128, 1), 256, 0, stream>>>(
        X, W1T, nullptr, nullptr, b1, nullptr, nullptr,
        dense_b, nullptr, nullptr, HID, FEAT, 1);

    // 2) Q/K/V = bf16(dense @ {Wq,Wk,Wv} (+bv on V)); BK=64, 8 iters
    gemm_mfma<0><<<dim3(NROWS / 64, DK / 128, 3), 256, 0, stream>>>(
        dense_b, WqT, WkT, WvT, nullptr, nullptr, bv,
        Qb, Kb, Vb, DK, HID, 0);

    // 3) a_raw (one wave per row, full TLP)
    gather_attn<<<NROWS / 4, 256, 0, stream>>>(Qb, Kb, sp, a_raw);
    // 4) pooled weighted sums + folded final epilogue (ticket)
    pool_kernel<<<NROWS / RPB, 256, 0, stream>>>(
        a_raw, Vb, P, Z, counter, Wout, bout, out);
}